// Round 1
// baseline (1130.852 us; speedup 1.0000x reference)
//
#include <hip/hip_runtime.h>
#include <hip/hip_bf16.h>

// ExpertMLPsV2: T=4096 tokens, H=2048 hidden, I=4096 intermediate, E=8 experts, TOPK=2.
// Sparse MoE: route -> per-expert gate/up GEMM (bf16 MFMA, fused silu*up*aff) -> down GEMM + atomic scatter.

constexpr int kT   = 4096;
constexpr int kH   = 2048;
constexpr int kI   = 4096;
constexpr int kE   = 8;
constexpr int kCap = 4096;   // max tokens per expert list

typedef __attribute__((ext_vector_type(8))) short bf16x8;
typedef __attribute__((ext_vector_type(4))) float f32x4;

// ---------------- workspace layout ----------------
constexpr size_t HSB_OFF   = 0;                                   // hs in bf16: T*H*2 = 16 MiB
constexpr size_t HSB_BYTES = (size_t)kT * kH * 2;
constexpr size_t HBUF_OFF  = HSB_OFF + HSB_BYTES;                 // h = silu(g)*u*w, bf16, (2T + 128 pad) x I
constexpr size_t HBUF_BYTES = (size_t)(2 * kT + 128) * kI * 2;    // ~65 MiB
constexpr size_t CNT_OFF   = HBUF_OFF + HBUF_BYTES;               // per-expert counts (8 ints)
constexpr size_t OFF_OFF   = CNT_OFF + 256;                       // per-expert row offsets (8 ints)
constexpr size_t LTOK_OFF  = OFF_OFF + 256;                       // token id lists  E*kCap int
constexpr size_t LW_OFF    = LTOK_OFF + (size_t)kE * kCap * 4;    // weight lists    E*kCap float
// total ~85.3 MiB

__device__ __forceinline__ unsigned short f2bf(float x) {   // RNE f32 -> bf16
  unsigned int u = __float_as_uint(x);
  u += 0x7FFFu + ((u >> 16) & 1u);
  return (unsigned short)(u >> 16);
}

__device__ __forceinline__ float silu_f(float x) { return x / (1.f + __expf(-x)); }

__device__ __forceinline__ void async_copy16(void* lds, const void* g) {
  __builtin_amdgcn_global_load_lds(
      (const __attribute__((address_space(1))) void*)g,
      (__attribute__((address_space(3))) void*)lds, 16, 0, 0);
}

// swizzled byte offset into a 128(row) x 64(k) bf16 LDS tile (row stride 128B).
// XOR at 16B granularity keeps ds_read_b128 / 8B writes contiguous.
__device__ __forceinline__ int swzB(int n, int kbyte) {
  return (n * 128 + kbyte) ^ (((n >> 2) & 7) << 4);
}

// write one transposed column: 4 bf16 along k at row n
__device__ __forceinline__ void wcol(char* base, int n, int kbyte,
                                     float f0, float f1, float f2, float f3) {
  uint2 v;
  v.x = (unsigned)f2bf(f0) | ((unsigned)f2bf(f1) << 16);
  v.y = (unsigned)f2bf(f2) | ((unsigned)f2bf(f3) << 16);
  *(uint2*)(base + swzB(n, kbyte)) = v;
}

// stage a 64(k) x 128(n) fp32 weight tile, transposed+converted, into (n,k) bf16 LDS tile.
// Wsrc points at expert's (K x N) matrix with row stride ld; tile origin (k0, n0).
__device__ __forceinline__ void stageW(const float* __restrict__ Wsrc, int ld,
                                       int k0, int n0, unsigned short* sW, int tid) {
  char* base = (char*)sW;
#pragma unroll
  for (int bb = 0; bb < 2; ++bb) {
    int b  = tid + bb * 256;        // 512 4x4 blocks
    int n4 = (b & 31) * 4;
    int k4 = (b >> 5) * 4;
    const float* src = Wsrc + (size_t)(k0 + k4) * ld + (n0 + n4);
    float4 r0 = *(const float4*)(src);
    float4 r1 = *(const float4*)(src + ld);
    float4 r2 = *(const float4*)(src + 2 * (size_t)ld);
    float4 r3 = *(const float4*)(src + 3 * (size_t)ld);
    int kb = k4 * 2;
    wcol(base, n4 + 0, kb, r0.x, r1.x, r2.x, r3.x);
    wcol(base, n4 + 1, kb, r0.y, r1.y, r2.y, r3.y);
    wcol(base, n4 + 2, kb, r0.z, r1.z, r2.z, r3.z);
    wcol(base, n4 + 3, kb, r0.w, r1.w, r2.w, r3.w);
  }
}

__device__ __forceinline__ bf16x8 readW(const unsigned short* sW, int n, int k) {
  return *(const bf16x8*)((const char*)sW + swzB(n, k * 2));
}
__device__ __forceinline__ bf16x8 readA(const unsigned short* sA, int m, int k) {
  return *(const bf16x8*)((const char*)sA + m * 128 + k * 2);
}

// ---------------- kernel 1: fp32 -> bf16 hidden states ----------------
__global__ void cvt_hs_kernel(const float* __restrict__ in, unsigned short* __restrict__ out) {
  size_t i = ((size_t)blockIdx.x * 256 + threadIdx.x) * 8;
  float4 a = *(const float4*)(in + i);
  float4 b = *(const float4*)(in + i + 4);
  uint4 v;
  v.x = (unsigned)f2bf(a.x) | ((unsigned)f2bf(a.y) << 16);
  v.y = (unsigned)f2bf(a.z) | ((unsigned)f2bf(a.w) << 16);
  v.z = (unsigned)f2bf(b.x) | ((unsigned)f2bf(b.y) << 16);
  v.w = (unsigned)f2bf(b.z) | ((unsigned)f2bf(b.w) << 16);
  *(uint4*)(out + i) = v;
}

// ---------------- kernel 2: routing ----------------
__global__ void route_kernel(const float* __restrict__ aff, const int* __restrict__ idx,
                             int* counts, int* ltok, float* lw) {
  int t = blockIdx.x * 256 + threadIdx.x;
  if (t >= kT) return;
  int e0 = idx[t * 2 + 0];
  int e1 = idx[t * 2 + 1];
  float a0 = aff[t * kE + e0];
  float a1 = aff[t * kE + e1];
  if (e0 == e1) {
    float w = a0 / fmaxf(fabsf(a0), 1e-12f);
    int s = atomicAdd(&counts[e0], 1);
    ltok[e0 * kCap + s] = t;
    lw[e0 * kCap + s]   = w;
  } else {
    float d = fmaxf(fabsf(a0) + fabsf(a1), 1e-12f);
    int s0 = atomicAdd(&counts[e0], 1);
    ltok[e0 * kCap + s0] = t;
    lw[e0 * kCap + s0]   = a0 / d;
    int s1 = atomicAdd(&counts[e1], 1);
    ltok[e1 * kCap + s1] = t;
    lw[e1 * kCap + s1]   = a1 / d;
  }
}

__global__ void prefix_kernel(const int* __restrict__ counts, int* offs) {
  if (threadIdx.x == 0 && blockIdx.x == 0) {
    int acc = 0;
    for (int e = 0; e < kE; ++e) { offs[e] = acc; acc += counts[e]; }
  }
}

// ---------------- kernel 3: gate/up GEMM + silu*up*aff -> h (bf16) ----------------
// grid (I/128, kCap/128, E), 256 threads. Swapped MFMA: D[n_local, m_local].
__global__ __launch_bounds__(256, 2)
void gemm_gu_kernel(const unsigned short* __restrict__ hsb,
                    const float* __restrict__ wg, const float* __restrict__ wu,
                    const int* __restrict__ counts, const int* __restrict__ offs,
                    const int* __restrict__ ltok, const float* __restrict__ lw,
                    unsigned short* __restrict__ hbuf) {
  __shared__ __attribute__((aligned(16))) unsigned short sWg[128 * 64];
  __shared__ __attribute__((aligned(16))) unsigned short sWu[128 * 64];
  __shared__ __attribute__((aligned(16))) unsigned short sAct[128 * 64];
  __shared__ int   sTok[128];
  __shared__ float sWt[128];

  const int e   = blockIdx.z;
  const int cnt = counts[e];
  const int m0  = blockIdx.y * 128;
  if (m0 >= cnt) return;
  const int n0   = blockIdx.x * 128;
  const int tid  = threadIdx.x;
  const int lane = tid & 63;
  const int wv   = tid >> 6;
  const int wn   = wv & 1;      // n half (64)
  const int wm   = wv >> 1;     // m half (64)

  if (tid < 128) {
    int s = m0 + tid;
    int tok = 0; float wgt = 0.f;
    if (s < cnt) { tok = ltok[e * kCap + s]; wgt = lw[e * kCap + s]; }
    sTok[tid] = tok; sWt[tid] = wgt;
  }
  __syncthreads();

  const float* wg_e = wg + (size_t)e * kH * kI;
  const float* wu_e = wu + (size_t)e * kH * kI;

  f32x4 accG[4][4] = {};
  f32x4 accU[4][4] = {};

  for (int kt = 0; kt < kH / 64; ++kt) {
    const int k0 = kt * 64;
    stageW(wg_e, kI, k0, n0, sWg, tid);
    stageW(wu_e, kI, k0, n0, sWu, tid);
#pragma unroll
    for (int it = 0; it < 4; ++it) {
      int c = it * 256 + tid;              // chunk of 8 bf16
      int row = c >> 3, col = (c & 7) * 8;
      async_copy16((char*)sAct + (size_t)c * 16,
                   hsb + (size_t)sTok[row] * kH + k0 + col);
    }
    __syncthreads();
#pragma unroll
    for (int kf = 0; kf < 2; ++kf) {
      const int kk = kf * 32 + (lane >> 4) * 8;
      bf16x8 aG[4], aU[4], bA[4];
#pragma unroll
      for (int i = 0; i < 4; ++i) {
        aG[i] = readW(sWg, wn * 64 + i * 16 + (lane & 15), kk);
        aU[i] = readW(sWu, wn * 64 + i * 16 + (lane & 15), kk);
        bA[i] = readA(sAct, wm * 64 + i * 16 + (lane & 15), kk);
      }
#pragma unroll
      for (int i = 0; i < 4; ++i)
#pragma unroll
        for (int j = 0; j < 4; ++j) {
          accG[i][j] = __builtin_amdgcn_mfma_f32_16x16x32_bf16(aG[i], bA[j], accG[i][j], 0, 0, 0);
          accU[i][j] = __builtin_amdgcn_mfma_f32_16x16x32_bf16(aU[i], bA[j], accU[i][j], 0, 0, 0);
        }
    }
    __syncthreads();
  }

  // epilogue: h = silu(g)*u*aff -> bf16, 4 consecutive I-columns per lane-frag
  const int lrow = (lane >> 4) * 4;
  const int lcol = lane & 15;
  const size_t rowbase = (size_t)(offs[e] + m0);
#pragma unroll
  for (int i = 0; i < 4; ++i) {
    const int ncol = n0 + wn * 64 + i * 16 + lrow;
#pragma unroll
    for (int j = 0; j < 4; ++j) {
      const int mloc = wm * 64 + j * 16 + lcol;
      if (m0 + mloc < cnt) {
        const float wgt = sWt[mloc];
        f32x4 g = accG[i][j], u = accU[i][j];
        float h0 = silu_f(g[0]) * u[0] * wgt;
        float h1 = silu_f(g[1]) * u[1] * wgt;
        float h2 = silu_f(g[2]) * u[2] * wgt;
        float h3 = silu_f(g[3]) * u[3] * wgt;
        uint2 v;
        v.x = (unsigned)f2bf(h0) | ((unsigned)f2bf(h1) << 16);
        v.y = (unsigned)f2bf(h2) | ((unsigned)f2bf(h3) << 16);
        *(uint2*)(hbuf + (rowbase + mloc) * kI + ncol) = v;
      }
    }
  }
}

// ---------------- kernel 4: down GEMM + atomic scatter-add ----------------
// grid (H/128, kCap/128, E), 256 threads.
__global__ __launch_bounds__(256, 2)
void gemm_dn_kernel(const unsigned short* __restrict__ hbuf,
                    const float* __restrict__ wd,
                    const int* __restrict__ counts, const int* __restrict__ offs,
                    const int* __restrict__ ltok, float* __restrict__ out) {
  __shared__ __attribute__((aligned(16))) unsigned short sW[128 * 64];
  __shared__ __attribute__((aligned(16))) unsigned short sAct[128 * 64];
  __shared__ int sTok[128];

  const int e   = blockIdx.z;
  const int cnt = counts[e];
  const int m0  = blockIdx.y * 128;
  if (m0 >= cnt) return;
  const int n0   = blockIdx.x * 128;
  const int tid  = threadIdx.x;
  const int lane = tid & 63;
  const int wv   = tid >> 6;
  const int wn   = wv & 1;
  const int wm   = wv >> 1;
  const int base_row = offs[e] + m0;

  if (tid < 128) {
    int s = m0 + tid;
    sTok[tid] = (s < cnt) ? ltok[e * kCap + s] : 0;
  }
  __syncthreads();

  const float* wd_e = wd + (size_t)e * kI * kH;
  f32x4 acc[4][4] = {};

  for (int kt = 0; kt < kI / 64; ++kt) {
    const int k0 = kt * 64;
    stageW(wd_e, kH, k0, n0, sW, tid);
#pragma unroll
    for (int it = 0; it < 4; ++it) {
      int c = it * 256 + tid;
      int row = c >> 3, col = (c & 7) * 8;
      async_copy16((char*)sAct + (size_t)c * 16,
                   hbuf + (size_t)(base_row + row) * kI + k0 + col);
    }
    __syncthreads();
#pragma unroll
    for (int kf = 0; kf < 2; ++kf) {
      const int kk = kf * 32 + (lane >> 4) * 8;
      bf16x8 aW[4], bA[4];
#pragma unroll
      for (int i = 0; i < 4; ++i) {
        aW[i] = readW(sW, wn * 64 + i * 16 + (lane & 15), kk);
        bA[i] = readA(sAct, wm * 64 + i * 16 + (lane & 15), kk);
      }
#pragma unroll
      for (int i = 0; i < 4; ++i)
#pragma unroll
        for (int j = 0; j < 4; ++j)
          acc[i][j] = __builtin_amdgcn_mfma_f32_16x16x32_bf16(aW[i], bA[j], acc[i][j], 0, 0, 0);
    }
    __syncthreads();
  }

  const int lrow = (lane >> 4) * 4;
  const int lcol = lane & 15;
#pragma unroll
  for (int i = 0; i < 4; ++i) {
    const int ncol = n0 + wn * 64 + i * 16 + lrow;
#pragma unroll
    for (int j = 0; j < 4; ++j) {
      const int mloc = wm * 64 + j * 16 + lcol;
      if (m0 + mloc < cnt) {
        float* op = out + (size_t)sTok[mloc] * kH + ncol;
        atomicAdd(op + 0, acc[i][j][0]);
        atomicAdd(op + 1, acc[i][j][1]);
        atomicAdd(op + 2, acc[i][j][2]);
        atomicAdd(op + 3, acc[i][j][3]);
      }
    }
  }
}

// ---------------- launcher ----------------
extern "C" void kernel_launch(void* const* d_in, const int* in_sizes, int n_in,
                              void* d_out, int out_size, void* d_ws, size_t ws_size,
                              hipStream_t stream) {
  const float* hs   = (const float*)d_in[0];
  const float* aff  = (const float*)d_in[1];
  const int*   eidx = (const int*)d_in[2];
  const float* wg   = (const float*)d_in[3];
  const float* wu   = (const float*)d_in[4];
  const float* wd   = (const float*)d_in[5];
  float* out = (float*)d_out;

  char* ws = (char*)d_ws;
  unsigned short* hsb   = (unsigned short*)(ws + HSB_OFF);
  unsigned short* hbuf  = (unsigned short*)(ws + HBUF_OFF);
  int*            cnts  = (int*)(ws + CNT_OFF);
  int*            offs  = (int*)(ws + OFF_OFF);
  int*            ltok  = (int*)(ws + LTOK_OFF);
  float*          lwgt  = (float*)(ws + LW_OFF);

  hipMemsetAsync(cnts, 0, kE * sizeof(int), stream);
  hipMemsetAsync(out, 0, (size_t)kT * kH * sizeof(float), stream);

  cvt_hs_kernel<<<(kT * kH) / (256 * 8), 256, 0, stream>>>(hs, hsb);
  route_kernel<<<kT / 256, 256, 0, stream>>>(aff, eidx, cnts, ltok, lwgt);
  prefix_kernel<<<1, 64, 0, stream>>>(cnts, offs);

  gemm_gu_kernel<<<dim3(kI / 128, kCap / 128, kE), 256, 0, stream>>>(
      hsb, wg, wu, cnts, offs, ltok, lwgt, hbuf);
  gemm_dn_kernel<<<dim3(kH / 128, kCap / 128, kE), 256, 0, stream>>>(
      hbuf, wd, cnts, offs, ltok, out);
}

// Round 2
// 904.231 us; speedup vs baseline: 1.2506x; 1.2506x over previous
//
#include <hip/hip_runtime.h>
#include <hip/hip_bf16.h>

// ExpertMLPsV2: T=4096, H=2048, I=4096, E=8, TOPK=2.
// route -> pre-transpose+convert weights to bf16 (N,K) -> gate/up GEMM (DMA-staged,
// swizzled, fused silu*up*aff) -> down GEMM + atomic scatter.

constexpr int kT   = 4096;
constexpr int kH   = 2048;
constexpr int kI   = 4096;
constexpr int kE   = 8;
constexpr int kCap = 4096;

typedef __attribute__((ext_vector_type(8))) short bf16x8;
typedef __attribute__((ext_vector_type(4))) float f32x4;

// ---------------- workspace layout ----------------
constexpr size_t HSB_OFF   = 0;                                   // hs bf16: 16 MiB
constexpr size_t HSB_BYTES = (size_t)kT * kH * 2;
constexpr size_t HBUF_OFF  = HSB_OFF + HSB_BYTES;                 // h bf16 (2T+128) x I
constexpr size_t HBUF_BYTES = (size_t)(2 * kT + 128) * kI * 2;
constexpr size_t CNT_OFF   = HBUF_OFF + HBUF_BYTES;
constexpr size_t OFF_OFF   = CNT_OFF + 256;
constexpr size_t LTOK_OFF  = OFF_OFF + 256;
constexpr size_t LW_OFF    = LTOK_OFF + (size_t)kE * kCap * 4;
constexpr size_t WGT_OFF   = LW_OFF + (size_t)kE * kCap * 4;      // wg^T bf16 (E,I,H)
constexpr size_t WMAT_B    = (size_t)kE * kH * kI * 2;            // 128 MiB each
constexpr size_t WUT_OFF   = WGT_OFF + WMAT_B;
constexpr size_t WDT_OFF   = WUT_OFF + WMAT_B;                    // wd^T bf16 (E,H,I)
// total ~488 MiB

__device__ __forceinline__ unsigned short f2bf(float x) {   // RNE f32 -> bf16
  unsigned int u = __float_as_uint(x);
  u += 0x7FFFu + ((u >> 16) & 1u);
  return (unsigned short)(u >> 16);
}

__device__ __forceinline__ float silu_f(float x) { return x / (1.f + __expf(-x)); }

__device__ __forceinline__ void async_copy16(void* lds, const void* g) {
  __builtin_amdgcn_global_load_lds(
      (const __attribute__((address_space(1))) void*)g,
      (__attribute__((address_space(3))) void*)lds, 16, 0, 0);
}

// Swizzled read from a [128 rows][64 k] bf16 tile: slot (16B) XOR'd with row&7.
// Staging puts global slot (s ^ (row&7)) at physical slot s, so read of logical
// slot l at physical l^(row&7) returns logical data. kk is bf16 index, mult of 8.
__device__ __forceinline__ bf16x8 readT(const unsigned short* s, int row, int kk) {
  return *(const bf16x8*)((const char*)s + row * 128 + ((((kk >> 3) ^ row) & 7) << 4));
}

// ---------------- kernel 1: fp32 -> bf16 hidden states ----------------
__global__ void cvt_hs_kernel(const float* __restrict__ in, unsigned short* __restrict__ out) {
  size_t i = ((size_t)blockIdx.x * 256 + threadIdx.x) * 8;
  float4 a = *(const float4*)(in + i);
  float4 b = *(const float4*)(in + i + 4);
  uint4 v;
  v.x = (unsigned)f2bf(a.x) | ((unsigned)f2bf(a.y) << 16);
  v.y = (unsigned)f2bf(a.z) | ((unsigned)f2bf(a.w) << 16);
  v.z = (unsigned)f2bf(b.x) | ((unsigned)f2bf(b.y) << 16);
  v.w = (unsigned)f2bf(b.z) | ((unsigned)f2bf(b.w) << 16);
  *(uint4*)(out + i) = v;
}

// ---------------- kernel 1b: transpose+convert weights (K,N) f32 -> (N,K) bf16 ----
__global__ __launch_bounds__(256)
void tcvt_kernel(const float* __restrict__ src, unsigned short* __restrict__ dst,
                 int K, int N) {
  __shared__ __attribute__((aligned(16))) unsigned short s[64][72];  // stride 144B = 9x16B
  const size_t mat = (size_t)K * N;
  const float* S = src + (size_t)blockIdx.z * mat;
  unsigned short* D = dst + (size_t)blockIdx.z * mat;
  const int k0 = blockIdx.y * 64, n0 = blockIdx.x * 64;
  const int t  = threadIdx.x;
  // 4x4 block transpose per thread
  const int n4 = (t & 15) * 4;
  const int k4 = (t >> 4) * 4;
  const float* p0 = S + (size_t)(k0 + k4) * N + n0 + n4;
  float4 r0 = *(const float4*)(p0);
  float4 r1 = *(const float4*)(p0 + N);
  float4 r2 = *(const float4*)(p0 + 2 * (size_t)N);
  float4 r3 = *(const float4*)(p0 + 3 * (size_t)N);
  {
    uint2 v;
    v.x = (unsigned)f2bf(r0.x) | ((unsigned)f2bf(r1.x) << 16);
    v.y = (unsigned)f2bf(r2.x) | ((unsigned)f2bf(r3.x) << 16);
    *(uint2*)(&s[n4 + 0][k4]) = v;
    v.x = (unsigned)f2bf(r0.y) | ((unsigned)f2bf(r1.y) << 16);
    v.y = (unsigned)f2bf(r2.y) | ((unsigned)f2bf(r3.y) << 16);
    *(uint2*)(&s[n4 + 1][k4]) = v;
    v.x = (unsigned)f2bf(r0.z) | ((unsigned)f2bf(r1.z) << 16);
    v.y = (unsigned)f2bf(r2.z) | ((unsigned)f2bf(r3.z) << 16);
    *(uint2*)(&s[n4 + 2][k4]) = v;
    v.x = (unsigned)f2bf(r0.w) | ((unsigned)f2bf(r1.w) << 16);
    v.y = (unsigned)f2bf(r2.w) | ((unsigned)f2bf(r3.w) << 16);
    *(uint2*)(&s[n4 + 3][k4]) = v;
  }
  __syncthreads();
  const int nn = t >> 3;
  const int kc = (t & 7) * 8;
#pragma unroll
  for (int i = 0; i < 2; ++i) {
    const int n = nn + i * 32;
    uint4 v = *(const uint4*)(&s[n][kc]);
    *(uint4*)(D + (size_t)(n0 + n) * K + k0 + kc) = v;
  }
}

// ---------------- kernel 2: routing ----------------
__global__ void route_kernel(const float* __restrict__ aff, const int* __restrict__ idx,
                             int* counts, int* ltok, float* lw) {
  int t = blockIdx.x * 256 + threadIdx.x;
  if (t >= kT) return;
  int e0 = idx[t * 2 + 0];
  int e1 = idx[t * 2 + 1];
  float a0 = aff[t * kE + e0];
  float a1 = aff[t * kE + e1];
  if (e0 == e1) {
    float w = a0 / fmaxf(fabsf(a0), 1e-12f);
    int s = atomicAdd(&counts[e0], 1);
    ltok[e0 * kCap + s] = t;
    lw[e0 * kCap + s]   = w;
  } else {
    float d = fmaxf(fabsf(a0) + fabsf(a1), 1e-12f);
    int s0 = atomicAdd(&counts[e0], 1);
    ltok[e0 * kCap + s0] = t;
    lw[e0 * kCap + s0]   = a0 / d;
    int s1 = atomicAdd(&counts[e1], 1);
    ltok[e1 * kCap + s1] = t;
    lw[e1 * kCap + s1]   = a1 / d;
  }
}

__global__ void prefix_kernel(const int* __restrict__ counts, int* offs) {
  if (threadIdx.x == 0 && blockIdx.x == 0) {
    int acc = 0;
    for (int e = 0; e < kE; ++e) { offs[e] = acc; acc += counts[e]; }
  }
}

// ---------------- kernel 3: gate/up GEMM + silu*up*aff -> h (bf16) ----------------
// grid (I/128, kCap/128, E), 256 threads. All operands DMA-staged, swizzled.
__global__ __launch_bounds__(256, 2)
void gemm_gu_kernel(const unsigned short* __restrict__ hsb,
                    const unsigned short* __restrict__ wgT,   // (E, I, H) bf16
                    const unsigned short* __restrict__ wuT,
                    const int* __restrict__ counts, const int* __restrict__ offs,
                    const int* __restrict__ ltok, const float* __restrict__ lw,
                    unsigned short* __restrict__ hbuf) {
  __shared__ __attribute__((aligned(16))) unsigned short sWg[128 * 64];
  __shared__ __attribute__((aligned(16))) unsigned short sWu[128 * 64];
  __shared__ __attribute__((aligned(16))) unsigned short sAct[128 * 64];
  __shared__ int   sTok[128];
  __shared__ float sWt[128];

  const int e   = blockIdx.z;
  const int cnt = counts[e];
  const int m0  = blockIdx.y * 128;
  if (m0 >= cnt) return;
  const int n0   = blockIdx.x * 128;
  const int tid  = threadIdx.x;
  const int lane = tid & 63;
  const int wv   = tid >> 6;
  const int wn   = wv & 1;
  const int wm   = wv >> 1;

  if (tid < 128) {
    int s = m0 + tid;
    int tok = 0; float wgt = 0.f;
    if (s < cnt) { tok = ltok[e * kCap + s]; wgt = lw[e * kCap + s]; }
    sTok[tid] = tok; sWt[tid] = wgt;
  }
  __syncthreads();

  const unsigned short* wg_e = wgT + (size_t)e * kI * kH;
  const unsigned short* wu_e = wuT + (size_t)e * kI * kH;

  f32x4 accG[4][4] = {};
  f32x4 accU[4][4] = {};

  for (int kt = 0; kt < kH / 64; ++kt) {
    const int k0 = kt * 64;
#pragma unroll
    for (int it = 0; it < 4; ++it) {
      const int c   = it * 256 + tid;      // 16B chunk index, wave-linear
      const int row = c >> 3;
      const int kof = k0 + ((((c & 7) ^ row) & 7) << 3);   // source pre-swizzle
      async_copy16((char*)sWg + (size_t)c * 16, wg_e + (size_t)(n0 + row) * kH + kof);
      async_copy16((char*)sWu + (size_t)c * 16, wu_e + (size_t)(n0 + row) * kH + kof);
      async_copy16((char*)sAct + (size_t)c * 16, hsb + (size_t)sTok[row] * kH + kof);
    }
    __syncthreads();   // compiler drains vmcnt before barrier
#pragma unroll
    for (int kf = 0; kf < 2; ++kf) {
      const int kk = kf * 32 + (lane >> 4) * 8;
      bf16x8 aG[4], aU[4], bA[4];
#pragma unroll
      for (int i = 0; i < 4; ++i) {
        aG[i] = readT(sWg, wn * 64 + i * 16 + (lane & 15), kk);
        aU[i] = readT(sWu, wn * 64 + i * 16 + (lane & 15), kk);
        bA[i] = readT(sAct, wm * 64 + i * 16 + (lane & 15), kk);
      }
#pragma unroll
      for (int i = 0; i < 4; ++i)
#pragma unroll
        for (int j = 0; j < 4; ++j) {
          accG[i][j] = __builtin_amdgcn_mfma_f32_16x16x32_bf16(aG[i], bA[j], accG[i][j], 0, 0, 0);
          accU[i][j] = __builtin_amdgcn_mfma_f32_16x16x32_bf16(aU[i], bA[j], accU[i][j], 0, 0, 0);
        }
    }
    __syncthreads();
  }

  const int lrow = (lane >> 4) * 4;
  const int lcol = lane & 15;
  const size_t rowbase = (size_t)(offs[e] + m0);
#pragma unroll
  for (int i = 0; i < 4; ++i) {
    const int ncol = n0 + wn * 64 + i * 16 + lrow;
#pragma unroll
    for (int j = 0; j < 4; ++j) {
      const int mloc = wm * 64 + j * 16 + lcol;
      if (m0 + mloc < cnt) {
        const float wgt = sWt[mloc];
        f32x4 g = accG[i][j], u = accU[i][j];
        float h0 = silu_f(g[0]) * u[0] * wgt;
        float h1 = silu_f(g[1]) * u[1] * wgt;
        float h2 = silu_f(g[2]) * u[2] * wgt;
        float h3 = silu_f(g[3]) * u[3] * wgt;
        uint2 v;
        v.x = (unsigned)f2bf(h0) | ((unsigned)f2bf(h1) << 16);
        v.y = (unsigned)f2bf(h2) | ((unsigned)f2bf(h3) << 16);
        *(uint2*)(hbuf + ((rowbase + mloc) * kI + ncol)) = v;
      }
    }
  }
}

// ---------------- kernel 4: down GEMM + atomic scatter-add ----------------
// grid (H/128, kCap/128, E), 256 threads.
__global__ __launch_bounds__(256, 3)
void gemm_dn_kernel(const unsigned short* __restrict__ hbuf,
                    const unsigned short* __restrict__ wdT,   // (E, H, I) bf16
                    const int* __restrict__ counts, const int* __restrict__ offs,
                    const int* __restrict__ ltok, float* __restrict__ out) {
  __shared__ __attribute__((aligned(16))) unsigned short sW[128 * 64];
  __shared__ __attribute__((aligned(16))) unsigned short sAct[128 * 64];
  __shared__ int sTok[128];

  const int e   = blockIdx.z;
  const int cnt = counts[e];
  const int m0  = blockIdx.y * 128;
  if (m0 >= cnt) return;
  const int n0   = blockIdx.x * 128;
  const int tid  = threadIdx.x;
  const int lane = tid & 63;
  const int wv   = tid >> 6;
  const int wn   = wv & 1;
  const int wm   = wv >> 1;
  const int base_row = offs[e] + m0;

  if (tid < 128) {
    int s = m0 + tid;
    sTok[tid] = (s < cnt) ? ltok[e * kCap + s] : 0;
  }
  __syncthreads();

  const unsigned short* wd_e = wdT + (size_t)e * kH * kI;
  f32x4 acc[4][4] = {};

  for (int kt = 0; kt < kI / 64; ++kt) {
    const int k0 = kt * 64;
#pragma unroll
    for (int it = 0; it < 4; ++it) {
      const int c   = it * 256 + tid;
      const int row = c >> 3;
      const int kof = k0 + ((((c & 7) ^ row) & 7) << 3);
      async_copy16((char*)sW + (size_t)c * 16, wd_e + (size_t)(n0 + row) * kI + kof);
      async_copy16((char*)sAct + (size_t)c * 16,
                   hbuf + (size_t)(base_row + row) * kI + kof);
    }
    __syncthreads();
#pragma unroll
    for (int kf = 0; kf < 2; ++kf) {
      const int kk = kf * 32 + (lane >> 4) * 8;
      bf16x8 aW[4], bA[4];
#pragma unroll
      for (int i = 0; i < 4; ++i) {
        aW[i] = readT(sW, wn * 64 + i * 16 + (lane & 15), kk);
        bA[i] = readT(sAct, wm * 64 + i * 16 + (lane & 15), kk);
      }
#pragma unroll
      for (int i = 0; i < 4; ++i)
#pragma unroll
        for (int j = 0; j < 4; ++j)
          acc[i][j] = __builtin_amdgcn_mfma_f32_16x16x32_bf16(aW[i], bA[j], acc[i][j], 0, 0, 0);
    }
    __syncthreads();
  }

  const int lrow = (lane >> 4) * 4;
  const int lcol = lane & 15;
#pragma unroll
  for (int i = 0; i < 4; ++i) {
    const int ncol = n0 + wn * 64 + i * 16 + lrow;
#pragma unroll
    for (int j = 0; j < 4; ++j) {
      const int mloc = wm * 64 + j * 16 + lcol;
      if (m0 + mloc < cnt) {
        float* op = out + (size_t)sTok[mloc] * kH + ncol;
        atomicAdd(op + 0, acc[i][j][0]);
        atomicAdd(op + 1, acc[i][j][1]);
        atomicAdd(op + 2, acc[i][j][2]);
        atomicAdd(op + 3, acc[i][j][3]);
      }
    }
  }
}

// ---------------- launcher ----------------
extern "C" void kernel_launch(void* const* d_in, const int* in_sizes, int n_in,
                              void* d_out, int out_size, void* d_ws, size_t ws_size,
                              hipStream_t stream) {
  const float* hs   = (const float*)d_in[0];
  const float* aff  = (const float*)d_in[1];
  const int*   eidx = (const int*)d_in[2];
  const float* wg   = (const float*)d_in[3];
  const float* wu   = (const float*)d_in[4];
  const float* wd   = (const float*)d_in[5];
  float* out = (float*)d_out;

  char* ws = (char*)d_ws;
  unsigned short* hsb  = (unsigned short*)(ws + HSB_OFF);
  unsigned short* hbuf = (unsigned short*)(ws + HBUF_OFF);
  int*            cnts = (int*)(ws + CNT_OFF);
  int*            offs = (int*)(ws + OFF_OFF);
  int*            ltok = (int*)(ws + LTOK_OFF);
  float*          lwgt = (float*)(ws + LW_OFF);
  unsigned short* wgT  = (unsigned short*)(ws + WGT_OFF);
  unsigned short* wuT  = (unsigned short*)(ws + WUT_OFF);
  unsigned short* wdT  = (unsigned short*)(ws + WDT_OFF);

  hipMemsetAsync(cnts, 0, kE * sizeof(int), stream);
  hipMemsetAsync(out, 0, (size_t)kT * kH * sizeof(float), stream);

  cvt_hs_kernel<<<(kT * kH) / (256 * 8), 256, 0, stream>>>(hs, hsb);
  route_kernel<<<kT / 256, 256, 0, stream>>>(aff, eidx, cnts, ltok, lwgt);
  prefix_kernel<<<1, 64, 0, stream>>>(cnts, offs);

  // weight transpose+convert: (E,K,N) f32 -> (E,N,K) bf16
  tcvt_kernel<<<dim3(kI / 64, kH / 64, kE), 256, 0, stream>>>(wg, wgT, kH, kI);
  tcvt_kernel<<<dim3(kI / 64, kH / 64, kE), 256, 0, stream>>>(wu, wuT, kH, kI);
  tcvt_kernel<<<dim3(kH / 64, kI / 64, kE), 256, 0, stream>>>(wd, wdT, kI, kH);

  gemm_gu_kernel<<<dim3(kI / 128, kCap / 128, kE), 256, 0, stream>>>(
      hsb, wgT, wuT, cnts, offs, ltok, lwgt, hbuf);
  gemm_dn_kernel<<<dim3(kH / 128, kCap / 128, kE), 256, 0, stream>>>(
      hbuf, wdT, cnts, offs, ltok, out);
}